// Round 1
// baseline (1184.341 us; speedup 1.0000x reference)
//
#include <hip/hip_runtime.h>
#include <stdint.h>

// Problem constants: B=4, S=2048, D=1024, E=8, F=4096, k=2 — FP32 I/O, bf16 MFMA compute
#define T_TOK   8192
#define DMODEL  1024
#define NEXP    8
#define FFN     4096
#define TASSIGN 16384   // T_TOK * k

typedef unsigned short u16;
typedef __attribute__((ext_vector_type(8))) short short8;   // MFMA bf16 A/B frag
typedef __attribute__((ext_vector_type(8))) u16 u16x8;
typedef __attribute__((ext_vector_type(4))) u16 u16x4;
typedef __attribute__((ext_vector_type(4))) float f32x4;    // MFMA C/D frag

__device__ __forceinline__ float bf2f(u16 u) {
  union { unsigned int i; float f; } v; v.i = ((unsigned int)u) << 16; return v.f;
}
__device__ __forceinline__ u16 f2bf(float f) {
  union { float f; unsigned int i; } v; v.f = f;
  unsigned int x = v.i;
  x += 0x7fffu + ((x >> 16) & 1u);   // round-to-nearest-even
  return (u16)(x >> 16);
}
// jax.nn.gelu default: approximate=True (tanh form)
__device__ __forceinline__ float gelu_tanh(float x) {
  float z = 0.7978845608028654f * x * (1.0f + 0.044715f * x * x);
  float t = 1.0f - 2.0f / (__expf(2.0f * z) + 1.0f);
  return 0.5f * x * (1.0f + t);
}
// async global->LDS, 16B per lane; LDS dest is wave-uniform base + lane*16
__device__ __forceinline__ void async16(const void* g, void* l) {
  __builtin_amdgcn_global_load_lds((__attribute__((address_space(1))) void*)g,
                                   (__attribute__((address_space(3))) void*)l,
                                   16, 0, 0);
}

// ---------------------------------------------------------------- meta init --
__global__ void init_kernel(int* __restrict__ meta) {
  if (threadIdx.x < 32) meta[threadIdx.x] = 0;
}

// ---------------------------------------------------------------- gating ----
__global__ void gate_kernel(const float* __restrict__ x, const float* __restrict__ Wg,
                            int* __restrict__ topi, float* __restrict__ topw,
                            int* __restrict__ counts, u16* __restrict__ xb) {
  __shared__ float sWg[DMODEL * NEXP];   // 32 KB
  int tid = threadIdx.x;
  for (int i = tid; i < DMODEL * NEXP / 4; i += 256)
    ((float4*)sWg)[i] = ((const float4*)Wg)[i];
  __syncthreads();

  int wave = tid >> 6, lane = tid & 63;
  int t = blockIdx.x * 4 + wave;       // grid=2048 -> t < 8192 always

  float acc[NEXP] = {0, 0, 0, 0, 0, 0, 0, 0};
  const float* xr = x + (size_t)t * DMODEL;
  u16* xbr = xb + (size_t)t * DMODEL;
  for (int d0 = 0; d0 < DMODEL; d0 += 128) {
    int d = d0 + lane * 2;
    float2 xx = *(const float2*)(xr + d);
    *(uint32_t*)(xbr + d) = (uint32_t)f2bf(xx.x) | ((uint32_t)f2bf(xx.y) << 16);
    const float* g0 = sWg + (size_t)d * NEXP;
#pragma unroll
    for (int e = 0; e < NEXP; e++)
      acc[e] += xx.x * g0[e] + xx.y * g0[NEXP + e];
  }
#pragma unroll
  for (int off = 32; off > 0; off >>= 1)
#pragma unroll
    for (int e = 0; e < NEXP; e++)
      acc[e] += __shfl_xor(acc[e], off, 64);

  if (lane == 0) {
    float v0 = -1e30f, v1 = -1e30f; int i0 = 0, i1 = 0;
#pragma unroll
    for (int e = 0; e < NEXP; e++) {           // strict > keeps earliest index on ties
      float v = acc[e];
      if (v > v0) { v1 = v0; i1 = i0; v0 = v; i0 = e; }
      else if (v > v1) { v1 = v; i1 = e; }
    }
    float e1 = __expf(v1 - v0);                // v1 <= v0
    float s = 1.0f / (1.0f + e1);
    topi[t * 2] = i0; topi[t * 2 + 1] = i1;
    topw[t * 2] = s;  topw[t * 2 + 1] = e1 * s;
    atomicAdd(&counts[i0], 1);
    atomicAdd(&counts[i1], 1);
  }
}

__global__ void scan_kernel(const int* __restrict__ counts, int* __restrict__ offsets,
                            int* __restrict__ cursors) {
  if (threadIdx.x == 0) {
    int s = 0;
    for (int e = 0; e < NEXP; e++) { offsets[e] = s; s += counts[e]; }
    offsets[NEXP] = s;
  }
  if (threadIdx.x < NEXP) cursors[threadIdx.x] = 0;
}

__global__ void build_kernel(const int* __restrict__ topi, const int* __restrict__ offsets,
                             int* __restrict__ cursors, int* __restrict__ perm,
                             int* __restrict__ slotrow) {
  int t = blockIdx.x * blockDim.x + threadIdx.x;
  if (t >= T_TOK) return;
#pragma unroll
  for (int s = 0; s < 2; s++) {
    int e = topi[t * 2 + s];
    int p = atomicAdd(&cursors[e], 1);
    int g = offsets[e] + p;
    perm[g] = t;
    slotrow[t * 2 + s] = g;
  }
}

// ------------------------------------------------------------- transpose ----
__global__ void transpose_kernel(const float* __restrict__ w1, const float* __restrict__ w2,
                                 u16* __restrict__ w1t, u16* __restrict__ w2t) {
  __shared__ u16 sh[64][72];   // +8 pad: keeps 16B store alignment, breaks bank stride
  int z = blockIdx.y;
  const float* src; u16* dst; int R, C;
  if (z < 8) { src = w1 + (size_t)z * (DMODEL * FFN); dst = w1t + (size_t)z * (FFN * DMODEL); R = DMODEL; C = FFN; }
  else       { src = w2 + (size_t)(z - 8) * (FFN * DMODEL); dst = w2t + (size_t)(z - 8) * (DMODEL * FFN); R = FFN; C = DMODEL; }
  int tilesC = C >> 6;
  int rt = blockIdx.x / tilesC, ct = blockIdx.x % tilesC;
  int tid = threadIdx.x;
#pragma unroll
  for (int i = 0; i < 2; i++) {
    int idx = i * 256 + tid;
    int r = idx >> 3, c8 = (idx & 7) * 8;
    const float* s = src + (size_t)(rt * 64 + r) * C + ct * 64 + c8;
    float4 v0 = *(const float4*)s, v1 = *(const float4*)(s + 4);
    u16* d = &sh[r][c8];
    d[0] = f2bf(v0.x); d[1] = f2bf(v0.y); d[2] = f2bf(v0.z); d[3] = f2bf(v0.w);
    d[4] = f2bf(v1.x); d[5] = f2bf(v1.y); d[6] = f2bf(v1.z); d[7] = f2bf(v1.w);
  }
  __syncthreads();
#pragma unroll
  for (int i = 0; i < 2; i++) {
    int idx = i * 256 + tid;
    int c = idx >> 3, r8 = (idx & 7) * 8;
    u16x8 v;
#pragma unroll
    for (int j = 0; j < 8; j++) v[j] = sh[r8 + j][c];
    *(u16x8*)(dst + (size_t)(ct * 64 + c) * R + rt * 64 + r8) = v;
  }
}

// --------------------------------------------- GEMM: 256x256 8-phase ---------
// C[i,n] = sum_k Arow(i)[k] * Bt[e][n][k]; A,Bt bf16 K-major.
// Port of the verified 8-phase template: BM=BN=256, BK=64, 8 waves (2Mx4N),
// 128 KiB LDS double-buffer, counted vmcnt(4), st_16x32 swizzle (linear LDS
// dest + pre-swizzled global source + swizzled ds_read), setprio around MFMA,
// expert<->XCD affinity grid swizzle (mtile-fastest for B-panel L2 reuse).
template <int K, int N, bool GATHER, bool GELU>
__global__ __launch_bounds__(512, 2) void gemm8_kernel(
    const u16* __restrict__ A, const u16* __restrict__ Bt, u16* __restrict__ C,
    const int* __restrict__ offsets, const int* __restrict__ perm) {
  __shared__ u16 S[65536];                 // A:2x16384, B:2x16384 u16 = 128 KiB
  constexpr int NTT = N / 256;             // n tiles
  constexpr int MT  = 32;                  // m tiles (covers worst case 8192 rows)
  constexpr int NKT = K / 64;              // K-tiles (16 or 64, always even, >=2)

  // grid = NEXP*NTT*MT; p%8 -> XCD -> expert; slot mtile-fastest (B-panel L2 reuse)
  int p = blockIdx.x;
  int e = p & 7;
  int slot = p >> 3;                       // [0, NTT*MT)
  int ntile = slot / MT;
  int mtile = slot % MT;

  int off = offsets[e];
  int nrows = offsets[e + 1] - off;
  if (mtile * 256 >= nrows) return;        // block-uniform: before any barrier

  int tid = threadIdx.x;
  int w = tid >> 6, l = tid & 63;
  int lm = l & 15, kq = l >> 4;
  int warp_m = w >> 2, warp_n = w & 3;
  int xr = ((l >> 2) & 1) << 4;            // u16-index XOR for swizzled ds_read (32B)

  // ---- staging source pointers (per-lane, source pre-swizzled: col chunk
  // (l&7)^(bit5(l)<<1) so the linear global_load_lds write lands the swizzled layout)
  int scol8 = ((l & 7) ^ (((l >> 5) & 1) << 1)) * 8;
  int rbase = w * 8 + (l >> 3);            // region row, + i*64 per issue
  const u16* aptr[2][2];                   // [q half][issue]
  const u16* bptr[2][2];
  const u16* bbase = Bt + (size_t)e * ((size_t)N * K);
#pragma unroll
  for (int q = 0; q < 2; q++)
#pragma unroll
    for (int i = 0; i < 2; i++) {
      int rr = rbase + i * 64;                         // [0,128)
      int rowA = (rr < 64 ? rr : rr + 64) + q * 64;    // A-q half rows
      int gm = mtile * 256 + rowA;
      int gmc = min(gm, nrows - 1);                    // clamp: duplicate last row
      int arow = GATHER ? perm[off + gmc] : (off + gmc);
      aptr[q][i] = A + (size_t)arow * K + scol8;
      int rowB = ((rr >> 5) << 6) + (rr & 31) + q * 32; // B-q stripe rows
      bptr[q][i] = bbase + (size_t)(ntile * 256 + rowB) * K + scol8;
    }
  // wave-uniform LDS dest row bases (linear write; swizzle is on source+read)
  int arb = w * 8;                          // A: + i*128 + q*64
  int brb = (w & 3) * 8 + (w >> 2) * 64;    // B: + i*128 + q*32
  u16* As_lds = S;
  u16* Bs_lds = S + 32768;

#define STAGE_A(q, buf, kt) do {                                                       \
    async16(aptr[q][0] + (kt) * 64, As_lds + (buf) * 16384 + (arb + (q) * 64) * 64);   \
    async16(aptr[q][1] + (kt) * 64, As_lds + (buf) * 16384 + (arb + 128 + (q) * 64) * 64); \
  } while (0)
#define STAGE_B(q, buf, kt) do {                                                       \
    async16(bptr[q][0] + (kt) * 64, Bs_lds + (buf) * 16384 + (brb + (q) * 32) * 64);   \
    async16(bptr[q][1] + (kt) * 64, Bs_lds + (buf) * 16384 + (brb + 128 + (q) * 32) * 64); \
  } while (0)

  f32x4 acc[8][4];
  f32x4 zero = {0.f, 0.f, 0.f, 0.f};
#pragma unroll
  for (int i = 0; i < 8; i++)
#pragma unroll
    for (int j = 0; j < 4; j++) acc[i][j] = zero;

// One phase: 12 ds_read_b128 || stage 1 half-tile -> barrier -> MFMA x16.
// vmcnt(4) only at phase 4/8 of each K-tile pair: keeps the 2 newest half-tile
// stages (4 loads) in flight across the barrier; everything older has landed.
#define GEMM8_PHASE(BUF, QM, QN, STAGE_STMT, DO_VM)                                    \
  {                                                                                    \
    short8 af[4][2], bf[2][2];                                                         \
    const u16* ab = As_lds + (BUF) * 16384;                                            \
    const u16* bb = Bs_lds + (BUF) * 16384;                                            \
    _Pragma("unroll") for (int fi = 0; fi < 4; fi++) {                                 \
      int ml = warp_m * 128 + ((QM) * 4 + fi) * 16 + lm;                               \
      _Pragma("unroll") for (int ks = 0; ks < 2; ks++)                                 \
        af[fi][ks] = *(const short8*)(ab + ((ml * 64 + ks * 32 + kq * 8) ^ xr));       \
    }                                                                                  \
    _Pragma("unroll") for (int fj = 0; fj < 2; fj++) {                                 \
      int nl = warp_n * 64 + ((QN) * 2 + fj) * 16 + lm;                                \
      _Pragma("unroll") for (int ks = 0; ks < 2; ks++)                                 \
        bf[fj][ks] = *(const short8*)(bb + ((nl * 64 + ks * 32 + kq * 8) ^ xr));       \
    }                                                                                  \
    STAGE_STMT;                                                                        \
    __builtin_amdgcn_s_barrier();                                                      \
    asm volatile("s_waitcnt lgkmcnt(0)" ::: "memory");                                 \
    __builtin_amdgcn_sched_barrier(0);                                                 \
    __builtin_amdgcn_s_setprio(1);                                                     \
    _Pragma("unroll") for (int fi = 0; fi < 4; fi++)                                   \
      _Pragma("unroll") for (int fj = 0; fj < 2; fj++)                                 \
        _Pragma("unroll") for (int ks = 0; ks < 2; ks++)                               \
          acc[(QM) * 4 + fi][(QN) * 2 + fj] = __builtin_amdgcn_mfma_f32_16x16x32_bf16( \
              af[fi][ks], bf[fj][ks], acc[(QM) * 4 + fi][(QN) * 2 + fj], 0, 0, 0);     \
    __builtin_amdgcn_s_setprio(0);                                                     \
    if (DO_VM) asm volatile("s_waitcnt vmcnt(4)" ::: "memory");                        \
    __builtin_amdgcn_s_barrier();                                                      \
  }

  // ---- prologue: tile0 fully + tile1 q0-halves (order = steady-state aging)
  STAGE_A(0, 0, 0); STAGE_B(0, 0, 0); STAGE_A(1, 0, 0); STAGE_B(1, 0, 0);
  STAGE_A(0, 1, 1); STAGE_B(0, 1, 1);
  asm volatile("s_waitcnt vmcnt(4)" ::: "memory");   // tile0's 8 loads landed
  __builtin_amdgcn_s_barrier();

  for (int it = 0; it < NKT / 2; it++) {
    int kt1 = 2 * it + 1;
    int t2 = min(2 * it + 2, NKT - 1);     // clamped lookahead (keeps vmcnt counts exact)
    int t3 = min(2 * it + 3, NKT - 1);
    // K-tile 2it from buf0; stage schedule: r0:A-q1(kt+1)->buf1, r1:B-q1(kt+1)->buf1,
    // r2:A-q0(kt+2)->buf0, r3:B-q0(kt+2)->buf0  (each region staged 1 phase after death)
    GEMM8_PHASE(0, 0, 0, STAGE_A(1, 1, kt1), 0)
    GEMM8_PHASE(0, 0, 1, STAGE_B(1, 1, kt1), 0)
    GEMM8_PHASE(0, 1, 0, STAGE_A(0, 0, t2), 0)
    GEMM8_PHASE(0, 1, 1, STAGE_B(0, 0, t2), 1)
    // K-tile 2it+1 from buf1
    GEMM8_PHASE(1, 0, 0, STAGE_A(1, 0, t2), 0)
    GEMM8_PHASE(1, 0, 1, STAGE_B(1, 0, t2), 0)
    GEMM8_PHASE(1, 1, 0, STAGE_A(0, 1, t3), 0)
    GEMM8_PHASE(1, 1, 1, STAGE_B(0, 1, t3), 1)
  }

  asm volatile("s_waitcnt vmcnt(0)" ::: "memory");   // drain LDS-DMA before exit

  // C/D frag: col = lane&15, row = (lane>>4)*4 + reg (same convention as verified 128^2 kernel)
#pragma unroll
  for (int fi = 0; fi < 8; fi++) {
    int rowb = mtile * 256 + warp_m * 128 + fi * 16 + kq * 4;
#pragma unroll
    for (int r = 0; r < 4; r++) {
      int row = rowb + r;
      if (row < nrows) {
        u16* crow = C + (size_t)(off + row) * N + ntile * 256 + warp_n * 64 + lm;
#pragma unroll
        for (int fj = 0; fj < 4; fj++) {
          float v = acc[fi][fj][r];
          if (GELU) v = gelu_tanh(v);
          crow[fj * 16] = f2bf(v);
        }
      }
    }
  }
#undef STAGE_A
#undef STAGE_B
#undef GEMM8_PHASE
}

// --------------------------------------------- GEMM (fallback, fp32 B) -----
template <int K, int N, bool GATHER, bool GELU>
__global__ __launch_bounds__(256) void gemm_f_kernel(
    const u16* __restrict__ A, const float* __restrict__ B, u16* __restrict__ C,
    const int* __restrict__ offsets, const int* __restrict__ perm) {
  __shared__ u16 As[128 * 32];
  __shared__ u16 Bs[128 * 32];
  int e = blockIdx.z;
  int off = offsets[e];
  int nrows = offsets[e + 1] - off;
  int mtile = blockIdx.y;
  if (mtile * 128 >= nrows) return;
  int ntile = blockIdx.x;

  int tid = threadIdx.x;
  int wave = tid >> 6, lane = tid & 63;

  int rr = tid >> 2;
  int kc = (tid & 3) * 8;
  int m0 = mtile * 128 + rr;
  int mm0 = min(m0, nrows - 1);
  int mm1 = min(m0 + 64, nrows - 1);
  const u16 *arow0, *arow1;
  if (GATHER) {
    arow0 = A + (size_t)perm[off + mm0] * K + kc;
    arow1 = A + (size_t)perm[off + mm1] * K + kc;
  } else {
    arow0 = A + (size_t)(off + mm0) * K + kc;
    arow1 = A + (size_t)(off + mm1) * K + kc;
  }

  int kk2 = (tid >> 4) * 2;
  int n8  = (tid & 15) * 8;
  const float* brow0 = B + (size_t)e * ((size_t)K * N) + (size_t)kk2 * N
                         + (size_t)ntile * 128 + n8;
  const float* brow1 = brow0 + N;

  int wm = (wave >> 1) * 64, wn = (wave & 1) * 64;
  int lm = lane & 15, kq = lane >> 4;

  f32x4 acc[4][4];
  f32x4 zero = {0.f, 0.f, 0.f, 0.f};
#pragma unroll
  for (int i = 0; i < 4; i++)
#pragma unroll
    for (int j = 0; j < 4; j++) acc[i][j] = zero;

  uint32_t* bs32 = (uint32_t*)Bs;
  for (int k0 = 0; k0 < K; k0 += 32) {
    u16x8 av0 = *(const u16x8*)(arow0 + k0);
    u16x8 av1 = *(const u16x8*)(arow1 + k0);
    float4 b00 = *(const float4*)(brow0 + (size_t)k0 * N);
    float4 b01 = *(const float4*)(brow0 + (size_t)k0 * N + 4);
    float4 b10 = *(const float4*)(brow1 + (size_t)k0 * N);
    float4 b11 = *(const float4*)(brow1 + (size_t)k0 * N + 4);
    __syncthreads();
    *(u16x8*)(As + (size_t)rr * 32 + kc) = av0;
    *(u16x8*)(As + (size_t)(rr + 64) * 32 + kc) = av1;
    int wcol = kk2 >> 1;
    bs32[(size_t)(n8 + 0) * 16 + wcol] = (uint32_t)f2bf(b00.x) | ((uint32_t)f2bf(b10.x) << 16);
    bs32[(size_t)(n8 + 1) * 16 + wcol] = (uint32_t)f2bf(b00.y) | ((uint32_t)f2bf(b10.y) << 16);
    bs32[(size_t)(n8 + 2) * 16 + wcol] = (uint32_t)f2bf(b00.z) | ((uint32_t)f2bf(b10.z) << 16);
    bs32[(size_t)(n8 + 3) * 16 + wcol] = (uint32_t)f2bf(b00.w) | ((uint32_t)f2bf(b10.w) << 16);
    bs32[(size_t)(n8 + 4) * 16 + wcol] = (uint32_t)f2bf(b01.x) | ((uint32_t)f2bf(b11.x) << 16);
    bs32[(size_t)(n8 + 5) * 16 + wcol] = (uint32_t)f2bf(b01.y) | ((uint32_t)f2bf(b11.y) << 16);
    bs32[(size_t)(n8 + 6) * 16 + wcol] = (uint32_t)f2bf(b01.z) | ((uint32_t)f2bf(b11.z) << 16);
    bs32[(size_t)(n8 + 7) * 16 + wcol] = (uint32_t)f2bf(b01.w) | ((uint32_t)f2bf(b11.w) << 16);
    __syncthreads();
    short8 a[4], b[4];
#pragma unroll
    for (int i = 0; i < 4; i++) {
      a[i] = *(const short8*)(As + (size_t)(wm + i * 16 + lm) * 32 + kq * 8);
      b[i] = *(const short8*)(Bs + (size_t)(wn + i * 16 + lm) * 32 + kq * 8);
    }
#pragma unroll
    for (int i = 0; i < 4; i++)
#pragma unroll
      for (int j = 0; j < 4; j++)
        acc[i][j] = __builtin_amdgcn_mfma_f32_16x16x32_bf16(a[i], b[j], acc[i][j], 0, 0, 0);
  }

#pragma unroll
  for (int i = 0; i < 4; i++) {
    int rbase = mtile * 128 + wm + i * 16 + kq * 4;
#pragma unroll
    for (int r = 0; r < 4; r++) {
      int row = rbase + r;
      if (row < nrows) {
        u16* crow = C + (size_t)(off + row) * N + ntile * 128 + wn + lm;
#pragma unroll
        for (int j = 0; j < 4; j++) {
          float v = acc[i][j][r];
          if (GELU) v = gelu_tanh(v);
          crow[j * 16] = f2bf(v);
        }
      }
    }
  }
}

// --------------------------------------------------------------- combine ----
__global__ void combine_kernel(const u16* __restrict__ Y, const int* __restrict__ slotrow,
                               const float* __restrict__ topw, float* __restrict__ out) {
  int idx = blockIdx.x * 256 + threadIdx.x;   // 8192 tokens * 256 chunks of 4
  int t = idx >> 8;
  int c = (idx & 255) * 4;
  int g0 = slotrow[t * 2], g1 = slotrow[t * 2 + 1];
  float w0 = topw[t * 2], w1 = topw[t * 2 + 1];
  u16x4 y0 = *(const u16x4*)(Y + (size_t)g0 * DMODEL + c);
  u16x4 y1 = *(const u16x4*)(Y + (size_t)g1 * DMODEL + c);
  float4 o;
  o.x = w0 * bf2f(y0[0]) + w1 * bf2f(y1[0]);
  o.y = w0 * bf2f(y0[1]) + w1 * bf2f(y1[1]);
  o.z = w0 * bf2f(y0[2]) + w1 * bf2f(y1[2]);
  o.w = w0 * bf2f(y0[3]) + w1 * bf2f(y1[3]);
  *(float4*)(out + (size_t)t * DMODEL + c) = o;
}

// ---------------------------------------------------------------- launch ----
extern "C" void kernel_launch(void* const* d_in, const int* in_sizes, int n_in,
                              void* d_out, int out_size, void* d_ws, size_t ws_size,
                              hipStream_t stream) {
  const float* x  = (const float*)d_in[0];
  const float* Wg = (const float*)d_in[1];
  const float* w1 = (const float*)d_in[2];
  const float* w2 = (const float*)d_in[3];
  float* out = (float*)d_out;

  const size_t SZ_H   = (size_t)TASSIGN * FFN * 2;        // 128 MB
  const size_t SZ_W1T = (size_t)NEXP * FFN * DMODEL * 2;  //  64 MB (Y aliases: needs 32 MB)
  const size_t SZ_W2T = (size_t)NEXP * DMODEL * FFN * 2;  //  64 MB
  const size_t SZ_XB  = (size_t)T_TOK * DMODEL * 2;       //  16 MB
  const size_t SZ_Y   = (size_t)TASSIGN * DMODEL * 2;     //  32 MB
  const size_t SZ_SMALL = (size_t)TASSIGN * 4 * 4 + 4096;
  const size_t WS_FULL = SZ_H + SZ_W1T + SZ_W2T + SZ_XB + SZ_SMALL;   // ~272.3 MB

  uint8_t* ws = (uint8_t*)d_ws;
  bool fast = (ws_size >= WS_FULL);

  size_t o = 0;
  u16* H = (u16*)(ws + o); o += SZ_H;
  u16 *w1t = nullptr, *w2t = nullptr, *Y;
  if (fast) {
    w1t = (u16*)(ws + o); o += SZ_W1T;
    w2t = (u16*)(ws + o); o += SZ_W2T;
    Y = w1t;                       // w1t is dead once GEMM2 starts writing Y
  } else {
    Y = (u16*)(ws + o); o += SZ_Y;
  }
  u16* xb = (u16*)(ws + o); o += SZ_XB;
  int*   topi    = (int*)(ws + o);   o += (size_t)TASSIGN * 4;
  float* topw    = (float*)(ws + o); o += (size_t)TASSIGN * 4;
  int*   perm    = (int*)(ws + o);   o += (size_t)TASSIGN * 4;
  int*   slotrow = (int*)(ws + o);   o += (size_t)TASSIGN * 4;
  int*   meta    = (int*)(ws + o);
  int* counts = meta, *offsets = meta + 8, *cursors = meta + 17;

  init_kernel<<<1, 64, 0, stream>>>(meta);
  gate_kernel<<<T_TOK / 4, 256, 0, stream>>>(x, Wg, topi, topw, counts, xb);
  scan_kernel<<<1, 64, 0, stream>>>(counts, offsets, cursors);
  build_kernel<<<T_TOK / 256, 256, 0, stream>>>(topi, offsets, cursors, perm, slotrow);

  if (fast) {
    transpose_kernel<<<dim3(1024, 16), 256, 0, stream>>>(w1, w2, w1t, w2t);
    // grid = NEXP * (N/256) * 32, 512 threads, XCD/expert-affine swizzle inside
    gemm8_kernel<DMODEL, FFN, true, true>
        <<<NEXP * (FFN / 256) * 32, 512, 0, stream>>>(xb, w1t, H, offsets, perm);
    gemm8_kernel<FFN, DMODEL, false, false>
        <<<NEXP * (DMODEL / 256) * 32, 512, 0, stream>>>(H, w2t, Y, offsets, perm);
  } else {
    gemm_f_kernel<DMODEL, FFN, true, true>
        <<<dim3(FFN / 128, 64, NEXP), 256, 0, stream>>>(xb, w1, H, offsets, perm);
    gemm_f_kernel<FFN, DMODEL, false, false>
        <<<dim3(DMODEL / 128, 64, NEXP), 256, 0, stream>>>(H, w2, Y, offsets, perm);
  }
  combine_kernel<<<(T_TOK * DMODEL / 4) / 256, 256, 0, stream>>>(Y, slotrow, topw, out);
}

// Round 2
// 1063.790 us; speedup vs baseline: 1.1133x; 1.1133x over previous
//
#include <hip/hip_runtime.h>
#include <stdint.h>

// Problem constants: B=4, S=2048, D=1024, E=8, F=4096, k=2 — FP32 I/O, bf16 MFMA compute
#define T_TOK   8192
#define DMODEL  1024
#define NEXP    8
#define FFN     4096
#define TASSIGN 16384   // T_TOK * k

typedef unsigned short u16;
typedef __attribute__((ext_vector_type(8))) short short8;   // MFMA bf16 A/B frag
typedef __attribute__((ext_vector_type(8))) u16 u16x8;
typedef __attribute__((ext_vector_type(4))) u16 u16x4;
typedef __attribute__((ext_vector_type(4))) float f32x4;    // MFMA C/D frag

__device__ __forceinline__ float bf2f(u16 u) {
  union { unsigned int i; float f; } v; v.i = ((unsigned int)u) << 16; return v.f;
}
__device__ __forceinline__ u16 f2bf(float f) {
  union { float f; unsigned int i; } v; v.f = f;
  unsigned int x = v.i;
  x += 0x7fffu + ((x >> 16) & 1u);   // round-to-nearest-even
  return (u16)(x >> 16);
}
// jax.nn.gelu default: approximate=True (tanh form)
__device__ __forceinline__ float gelu_tanh(float x) {
  float z = 0.7978845608028654f * x * (1.0f + 0.044715f * x * x);
  float t = 1.0f - 2.0f / (__expf(2.0f * z) + 1.0f);
  return 0.5f * x * (1.0f + t);
}
// async global->LDS, 16B per lane; LDS dest is wave-uniform base + lane*16
__device__ __forceinline__ void async16(const void* g, void* l) {
  __builtin_amdgcn_global_load_lds((__attribute__((address_space(1))) void*)g,
                                   (__attribute__((address_space(3))) void*)l,
                                   16, 0, 0);
}

// ---------------------------------------------------------------- meta init --
__global__ void init_kernel(int* __restrict__ meta) {
  if (threadIdx.x < 32) meta[threadIdx.x] = 0;
}

// ---------------------------------------------------------------- gating ----
__global__ void gate_kernel(const float* __restrict__ x, const float* __restrict__ Wg,
                            int* __restrict__ topi, float* __restrict__ topw,
                            int* __restrict__ counts, u16* __restrict__ xb) {
  __shared__ float sWg[DMODEL * NEXP];   // 32 KB
  int tid = threadIdx.x;
  for (int i = tid; i < DMODEL * NEXP / 4; i += 256)
    ((float4*)sWg)[i] = ((const float4*)Wg)[i];
  __syncthreads();

  int wave = tid >> 6, lane = tid & 63;
  int t = blockIdx.x * 4 + wave;       // grid=2048 -> t < 8192 always

  float acc[NEXP] = {0, 0, 0, 0, 0, 0, 0, 0};
  const float* xr = x + (size_t)t * DMODEL;
  u16* xbr = xb + (size_t)t * DMODEL;
  for (int d0 = 0; d0 < DMODEL; d0 += 128) {
    int d = d0 + lane * 2;
    float2 xx = *(const float2*)(xr + d);
    *(uint32_t*)(xbr + d) = (uint32_t)f2bf(xx.x) | ((uint32_t)f2bf(xx.y) << 16);
    const float* g0 = sWg + (size_t)d * NEXP;
#pragma unroll
    for (int e = 0; e < NEXP; e++)
      acc[e] += xx.x * g0[e] + xx.y * g0[NEXP + e];
  }
#pragma unroll
  for (int off = 32; off > 0; off >>= 1)
#pragma unroll
    for (int e = 0; e < NEXP; e++)
      acc[e] += __shfl_xor(acc[e], off, 64);

  if (lane == 0) {
    float v0 = -1e30f, v1 = -1e30f; int i0 = 0, i1 = 0;
#pragma unroll
    for (int e = 0; e < NEXP; e++) {           // strict > keeps earliest index on ties
      float v = acc[e];
      if (v > v0) { v1 = v0; i1 = i0; v0 = v; i0 = e; }
      else if (v > v1) { v1 = v; i1 = e; }
    }
    float e1 = __expf(v1 - v0);                // v1 <= v0
    float s = 1.0f / (1.0f + e1);
    topi[t * 2] = i0; topi[t * 2 + 1] = i1;
    topw[t * 2] = s;  topw[t * 2 + 1] = e1 * s;
    atomicAdd(&counts[i0], 1);
    atomicAdd(&counts[i1], 1);
  }
}

__global__ void scan_kernel(const int* __restrict__ counts, int* __restrict__ offsets,
                            int* __restrict__ cursors) {
  if (threadIdx.x == 0) {
    int s = 0;
    for (int e = 0; e < NEXP; e++) { offsets[e] = s; s += counts[e]; }
    offsets[NEXP] = s;
  }
  if (threadIdx.x < NEXP) cursors[threadIdx.x] = 0;
}

__global__ void build_kernel(const int* __restrict__ topi, const int* __restrict__ offsets,
                             int* __restrict__ cursors, int* __restrict__ perm,
                             int* __restrict__ slotrow) {
  int t = blockIdx.x * blockDim.x + threadIdx.x;
  if (t >= T_TOK) return;
#pragma unroll
  for (int s = 0; s < 2; s++) {
    int e = topi[t * 2 + s];
    int p = atomicAdd(&cursors[e], 1);
    int g = offsets[e] + p;
    perm[g] = t;
    slotrow[t * 2 + s] = g;
  }
}

// ------------------------------------------------------------- transpose ----
__global__ void transpose_kernel(const float* __restrict__ w1, const float* __restrict__ w2,
                                 u16* __restrict__ w1t, u16* __restrict__ w2t) {
  __shared__ u16 sh[64][72];   // +8 pad: keeps 16B store alignment, breaks bank stride
  int z = blockIdx.y;
  const float* src; u16* dst; int R, C;
  if (z < 8) { src = w1 + (size_t)z * (DMODEL * FFN); dst = w1t + (size_t)z * (FFN * DMODEL); R = DMODEL; C = FFN; }
  else       { src = w2 + (size_t)(z - 8) * (FFN * DMODEL); dst = w2t + (size_t)(z - 8) * (DMODEL * FFN); R = FFN; C = DMODEL; }
  int tilesC = C >> 6;
  int rt = blockIdx.x / tilesC, ct = blockIdx.x % tilesC;
  int tid = threadIdx.x;
#pragma unroll
  for (int i = 0; i < 2; i++) {
    int idx = i * 256 + tid;
    int r = idx >> 3, c8 = (idx & 7) * 8;
    const float* s = src + (size_t)(rt * 64 + r) * C + ct * 64 + c8;
    float4 v0 = *(const float4*)s, v1 = *(const float4*)(s + 4);
    u16* d = &sh[r][c8];
    d[0] = f2bf(v0.x); d[1] = f2bf(v0.y); d[2] = f2bf(v0.z); d[3] = f2bf(v0.w);
    d[4] = f2bf(v1.x); d[5] = f2bf(v1.y); d[6] = f2bf(v1.z); d[7] = f2bf(v1.w);
  }
  __syncthreads();
#pragma unroll
  for (int i = 0; i < 2; i++) {
    int idx = i * 256 + tid;
    int c = idx >> 3, r8 = (idx & 7) * 8;
    u16x8 v;
#pragma unroll
    for (int j = 0; j < 8; j++) v[j] = sh[r8 + j][c];
    *(u16x8*)(dst + (size_t)(ct * 64 + c) * R + rt * 64 + r8) = v;
  }
}

// --------------------------------------------- GEMM: 256x256 8-phase ---------
// C[i,n] = sum_k Arow(i)[k] * Bt[e][n][k]; A,Bt bf16 K-major.
// 8-phase template: BM=BN=256, BK=64, 8 waves (2Mx4N), 128 KiB LDS double
// buffer, counted vmcnt(4), setprio around MFMA, expert<->XCD affinity.
// LDS swizzle (fixed this round): rows are 64 u16 = 128B; fragment reads have
// lanes 0-15 on consecutive rows at one 16B chunk -> 16-way bank conflict.
// Fix: chunk16 ^= (row&7) on BOTH sides — read addr XOR ((row&7)<<3) in u16,
// and staging source column chunk (l&7)^((l>>3)&7) (all stage row bases are
// multiples of 8, lane writes row base+(l>>3)), LDS dest stays linear (m104).
template <int K, int N, bool GATHER, bool GELU>
__global__ __launch_bounds__(512, 2) void gemm8_kernel(
    const u16* __restrict__ A, const u16* __restrict__ Bt, u16* __restrict__ C,
    const int* __restrict__ offsets, const int* __restrict__ perm) {
  __shared__ u16 S[65536];                 // A:2x16384, B:2x16384 u16 = 128 KiB
  constexpr int NTT = N / 256;             // n tiles
  constexpr int MT  = 32;                  // m tiles (covers worst case 8192 rows)
  constexpr int NKT = K / 64;              // K-tiles (16 or 64, always even, >=2)
  (void)NTT;

  // grid = NEXP*NTT*MT; p%8 -> XCD -> expert; slot mtile-fastest (B-panel L2 reuse)
  int p = blockIdx.x;
  int e = p & 7;
  int slot = p >> 3;                       // [0, NTT*MT)
  int ntile = slot / MT;
  int mtile = slot % MT;

  int off = offsets[e];
  int nrows = offsets[e + 1] - off;
  if (mtile * 256 >= nrows) return;        // block-uniform: safe before barriers

  int tid = threadIdx.x;
  int w = tid >> 6, l = tid & 63;
  int lm = l & 15, kq = l >> 4;
  int warp_m = w >> 2, warp_n = w & 3;
  int swz = (lm & 7) << 3;                 // u16-index XOR for swizzled ds_read

  // ---- staging source pointers (per-lane, source pre-swizzled so the linear
  // global_load_lds write lands the swizzled layout)
  int scol8 = ((l & 7) ^ ((l >> 3) & 7)) * 8;
  int rbase = w * 8 + (l >> 3);            // region row, + i*64 per issue
  const u16* aptr[2][2];                   // [q half][issue]
  const u16* bptr[2][2];
  const u16* bbase = Bt + (size_t)e * ((size_t)N * K);
#pragma unroll
  for (int q = 0; q < 2; q++)
#pragma unroll
    for (int i = 0; i < 2; i++) {
      int rr = rbase + i * 64;                         // [0,128)
      int rowA = (rr < 64 ? rr : rr + 64) + q * 64;    // A-q half rows
      int gm = mtile * 256 + rowA;
      int gmc = min(gm, nrows - 1);                    // clamp: duplicates last row
      int arow = GATHER ? perm[off + gmc] : (off + gmc);
      aptr[q][i] = A + (size_t)arow * K + scol8;
      int rowB = ((rr >> 5) << 6) + (rr & 31) + q * 32; // B-q stripe rows
      bptr[q][i] = bbase + (size_t)(ntile * 256 + rowB) * K + scol8;
    }
  // wave-uniform LDS dest row bases (linear write; swizzle is on source+read)
  int arb = w * 8;                          // A: + i*128 + q*64
  int brb = (w & 3) * 8 + (w >> 2) * 64;    // B: + i*128 + q*32
  u16* As_lds = S;
  u16* Bs_lds = S + 32768;

#define STAGE_A(q, buf, kt) do {                                                       \
    async16(aptr[q][0] + (kt) * 64, As_lds + (buf) * 16384 + (arb + (q) * 64) * 64);   \
    async16(aptr[q][1] + (kt) * 64, As_lds + (buf) * 16384 + (arb + 128 + (q) * 64) * 64); \
  } while (0)
#define STAGE_B(q, buf, kt) do {                                                       \
    async16(bptr[q][0] + (kt) * 64, Bs_lds + (buf) * 16384 + (brb + (q) * 32) * 64);   \
    async16(bptr[q][1] + (kt) * 64, Bs_lds + (buf) * 16384 + (brb + 128 + (q) * 32) * 64); \
  } while (0)

  f32x4 acc[8][4];
  f32x4 zero = {0.f, 0.f, 0.f, 0.f};
#pragma unroll
  for (int i = 0; i < 8; i++)
#pragma unroll
    for (int j = 0; j < 4; j++) acc[i][j] = zero;

// One phase: 12 ds_read_b128 || stage 1 half-tile -> barrier -> MFMA x16.
// vmcnt(4) only at phase 4/8 of each K-tile pair: keeps the 2 newest half-tile
// stages (4 loads) in flight across the barrier; everything older has landed.
#define GEMM8_PHASE(BUF, QM, QN, STAGE_STMT, DO_VM)                                    \
  {                                                                                    \
    short8 af[4][2], bf[2][2];                                                         \
    const u16* ab = As_lds + (BUF) * 16384;                                            \
    const u16* bb = Bs_lds + (BUF) * 16384;                                            \
    _Pragma("unroll") for (int fi = 0; fi < 4; fi++) {                                 \
      int ml = warp_m * 128 + ((QM) * 4 + fi) * 16 + lm;                               \
      _Pragma("unroll") for (int ks = 0; ks < 2; ks++)                                 \
        af[fi][ks] = *(const short8*)(ab + ml * 64 + ((ks * 32 + kq * 8) ^ swz));      \
    }                                                                                  \
    _Pragma("unroll") for (int fj = 0; fj < 2; fj++) {                                 \
      int nl = warp_n * 64 + ((QN) * 2 + fj) * 16 + lm;                                \
      _Pragma("unroll") for (int ks = 0; ks < 2; ks++)                                 \
        bf[fj][ks] = *(const short8*)(bb + nl * 64 + ((ks * 32 + kq * 8) ^ swz));      \
    }                                                                                  \
    STAGE_STMT;                                                                        \
    __builtin_amdgcn_s_barrier();                                                      \
    asm volatile("s_waitcnt lgkmcnt(0)" ::: "memory");                                 \
    __builtin_amdgcn_sched_barrier(0);                                                 \
    __builtin_amdgcn_s_setprio(1);                                                     \
    _Pragma("unroll") for (int fi = 0; fi < 4; fi++)                                   \
      _Pragma("unroll") for (int fj = 0; fj < 2; fj++)                                 \
        _Pragma("unroll") for (int ks = 0; ks < 2; ks++)                               \
          acc[(QM) * 4 + fi][(QN) * 2 + fj] = __builtin_amdgcn_mfma_f32_16x16x32_bf16( \
              af[fi][ks], bf[fj][ks], acc[(QM) * 4 + fi][(QN) * 2 + fj], 0, 0, 0);     \
    __builtin_amdgcn_s_setprio(0);                                                     \
    if (DO_VM) asm volatile("s_waitcnt vmcnt(4)" ::: "memory");                        \
    __builtin_amdgcn_s_barrier();                                                      \
  }

  // ---- prologue: tile0 fully + tile1 q0-halves (order = steady-state aging)
  STAGE_A(0, 0, 0); STAGE_B(0, 0, 0); STAGE_A(1, 0, 0); STAGE_B(1, 0, 0);
  STAGE_A(0, 1, 1); STAGE_B(0, 1, 1);
  asm volatile("s_waitcnt vmcnt(4)" ::: "memory");   // tile0's 8 loads landed
  __builtin_amdgcn_s_barrier();

  for (int it = 0; it < NKT / 2; it++) {
    int kt1 = 2 * it + 1;
    int t2 = min(2 * it + 2, NKT - 1);     // clamped lookahead (keeps vmcnt counts exact)
    int t3 = min(2 * it + 3, NKT - 1);
    // K-tile 2it from buf0; stage schedule: r0:A-q1(kt+1)->buf1, r1:B-q1(kt+1)->buf1,
    // r2:A-q0(kt+2)->buf0, r3:B-q0(kt+2)->buf0  (each region staged 1 phase after death)
    GEMM8_PHASE(0, 0, 0, STAGE_A(1, 1, kt1), 0)
    GEMM8_PHASE(0, 0, 1, STAGE_B(1, 1, kt1), 0)
    GEMM8_PHASE(0, 1, 0, STAGE_A(0, 0, t2), 0)
    GEMM8_PHASE(0, 1, 1, STAGE_B(0, 0, t2), 1)
    // K-tile 2it+1 from buf1
    GEMM8_PHASE(1, 0, 0, STAGE_A(1, 0, t2), 0)
    GEMM8_PHASE(1, 0, 1, STAGE_B(1, 0, t2), 0)
    GEMM8_PHASE(1, 1, 0, STAGE_A(0, 1, t3), 0)
    GEMM8_PHASE(1, 1, 1, STAGE_B(0, 1, t3), 1)
  }

  asm volatile("s_waitcnt vmcnt(0)" ::: "memory");   // drain LDS-DMA before exit

  // C/D frag: col = lane&15, row = (lane>>4)*4 + reg
#pragma unroll
  for (int fi = 0; fi < 8; fi++) {
    int rowb = mtile * 256 + warp_m * 128 + fi * 16 + kq * 4;
#pragma unroll
    for (int r = 0; r < 4; r++) {
      int row = rowb + r;
      if (row < nrows) {
        u16* crow = C + (size_t)(off + row) * N + ntile * 256 + warp_n * 64 + lm;
#pragma unroll
        for (int fj = 0; fj < 4; fj++) {
          float v = acc[fi][fj][r];
          if (GELU) v = gelu_tanh(v);
          crow[fj * 16] = f2bf(v);
        }
      }
    }
  }
#undef STAGE_A
#undef STAGE_B
#undef GEMM8_PHASE
}

// --------------------------------------------- GEMM (fallback, fp32 B) -----
template <int K, int N, bool GATHER, bool GELU>
__global__ __launch_bounds__(256) void gemm_f_kernel(
    const u16* __restrict__ A, const float* __restrict__ B, u16* __restrict__ C,
    const int* __restrict__ offsets, const int* __restrict__ perm) {
  __shared__ u16 As[128 * 32];
  __shared__ u16 Bs[128 * 32];
  int e = blockIdx.z;
  int off = offsets[e];
  int nrows = offsets[e + 1] - off;
  int mtile = blockIdx.y;
  if (mtile * 128 >= nrows) return;
  int ntile = blockIdx.x;

  int tid = threadIdx.x;
  int wave = tid >> 6, lane = tid & 63;

  int rr = tid >> 2;
  int kc = (tid & 3) * 8;
  int m0 = mtile * 128 + rr;
  int mm0 = min(m0, nrows - 1);
  int mm1 = min(m0 + 64, nrows - 1);
  const u16 *arow0, *arow1;
  if (GATHER) {
    arow0 = A + (size_t)perm[off + mm0] * K + kc;
    arow1 = A + (size_t)perm[off + mm1] * K + kc;
  } else {
    arow0 = A + (size_t)(off + mm0) * K + kc;
    arow1 = A + (size_t)(off + mm1) * K + kc;
  }

  int kk2 = (tid >> 4) * 2;
  int n8  = (tid & 15) * 8;
  const float* brow0 = B + (size_t)e * ((size_t)K * N) + (size_t)kk2 * N
                         + (size_t)ntile * 128 + n8;
  const float* brow1 = brow0 + N;

  int wm = (wave >> 1) * 64, wn = (wave & 1) * 64;
  int lm = lane & 15, kq = lane >> 4;

  f32x4 acc[4][4];
  f32x4 zero = {0.f, 0.f, 0.f, 0.f};
#pragma unroll
  for (int i = 0; i < 4; i++)
#pragma unroll
    for (int j = 0; j < 4; j++) acc[i][j] = zero;

  uint32_t* bs32 = (uint32_t*)Bs;
  for (int k0 = 0; k0 < K; k0 += 32) {
    u16x8 av0 = *(const u16x8*)(arow0 + k0);
    u16x8 av1 = *(const u16x8*)(arow1 + k0);
    float4 b00 = *(const float4*)(brow0 + (size_t)k0 * N);
    float4 b01 = *(const float4*)(brow0 + (size_t)k0 * N + 4);
    float4 b10 = *(const float4*)(brow1 + (size_t)k0 * N);
    float4 b11 = *(const float4*)(brow1 + (size_t)k0 * N + 4);
    __syncthreads();
    *(u16x8*)(As + (size_t)rr * 32 + kc) = av0;
    *(u16x8*)(As + (size_t)(rr + 64) * 32 + kc) = av1;
    int wcol = kk2 >> 1;
    bs32[(size_t)(n8 + 0) * 16 + wcol] = (uint32_t)f2bf(b00.x) | ((uint32_t)f2bf(b10.x) << 16);
    bs32[(size_t)(n8 + 1) * 16 + wcol] = (uint32_t)f2bf(b00.y) | ((uint32_t)f2bf(b10.y) << 16);
    bs32[(size_t)(n8 + 2) * 16 + wcol] = (uint32_t)f2bf(b00.z) | ((uint32_t)f2bf(b10.z) << 16);
    bs32[(size_t)(n8 + 3) * 16 + wcol] = (uint32_t)f2bf(b00.w) | ((uint32_t)f2bf(b10.w) << 16);
    bs32[(size_t)(n8 + 4) * 16 + wcol] = (uint32_t)f2bf(b01.x) | ((uint32_t)f2bf(b11.x) << 16);
    bs32[(size_t)(n8 + 5) * 16 + wcol] = (uint32_t)f2bf(b01.y) | ((uint32_t)f2bf(b11.y) << 16);
    bs32[(size_t)(n8 + 6) * 16 + wcol] = (uint32_t)f2bf(b01.z) | ((uint32_t)f2bf(b11.z) << 16);
    bs32[(size_t)(n8 + 7) * 16 + wcol] = (uint32_t)f2bf(b01.w) | ((uint32_t)f2bf(b11.w) << 16);
    __syncthreads();
    short8 a[4], b[4];
#pragma unroll
    for (int i = 0; i < 4; i++) {
      a[i] = *(const short8*)(As + (size_t)(wm + i * 16 + lm) * 32 + kq * 8);
      b[i] = *(const short8*)(Bs + (size_t)(wn + i * 16 + lm) * 32 + kq * 8);
    }
#pragma unroll
    for (int i = 0; i < 4; i++)
#pragma unroll
      for (int j = 0; j < 4; j++)
        acc[i][j] = __builtin_amdgcn_mfma_f32_16x16x32_bf16(a[i], b[j], acc[i][j], 0, 0, 0);
  }

#pragma unroll
  for (int i = 0; i < 4; i++) {
    int rbase = mtile * 128 + wm + i * 16 + kq * 4;
#pragma unroll
    for (int r = 0; r < 4; r++) {
      int row = rbase + r;
      if (row < nrows) {
        u16* crow = C + (size_t)(off + row) * N + ntile * 128 + wn + lm;
#pragma unroll
        for (int j = 0; j < 4; j++) {
          float v = acc[i][j][r];
          if (GELU) v = gelu_tanh(v);
          crow[j * 16] = f2bf(v);
        }
      }
    }
  }
}

// --------------------------------------------------------------- combine ----
__global__ void combine_kernel(const u16* __restrict__ Y, const int* __restrict__ slotrow,
                               const float* __restrict__ topw, float* __restrict__ out) {
  int idx = blockIdx.x * 256 + threadIdx.x;   // 8192 tokens * 256 chunks of 4
  int t = idx >> 8;
  int c = (idx & 255) * 4;
  int g0 = slotrow[t * 2], g1 = slotrow[t * 2 + 1];
  float w0 = topw[t * 2], w1 = topw[t * 2 + 1];
  u16x4 y0 = *(const u16x4*)(Y + (size_t)g0 * DMODEL + c);
  u16x4 y1 = *(const u16x4*)(Y + (size_t)g1 * DMODEL + c);
  float4 o;
  o.x = w0 * bf2f(y0[0]) + w1 * bf2f(y1[0]);
  o.y = w0 * bf2f(y0[1]) + w1 * bf2f(y1[1]);
  o.z = w0 * bf2f(y0[2]) + w1 * bf2f(y1[2]);
  o.w = w0 * bf2f(y0[3]) + w1 * bf2f(y1[3]);
  *(float4*)(out + (size_t)t * DMODEL + c) = o;
}

// ---------------------------------------------------------------- launch ----
extern "C" void kernel_launch(void* const* d_in, const int* in_sizes, int n_in,
                              void* d_out, int out_size, void* d_ws, size_t ws_size,
                              hipStream_t stream) {
  const float* x  = (const float*)d_in[0];
  const float* Wg = (const float*)d_in[1];
  const float* w1 = (const float*)d_in[2];
  const float* w2 = (const float*)d_in[3];
  float* out = (float*)d_out;

  const size_t SZ_H   = (size_t)TASSIGN * FFN * 2;        // 128 MB
  const size_t SZ_W1T = (size_t)NEXP * FFN * DMODEL * 2;  //  64 MB (Y aliases: needs 32 MB)
  const size_t SZ_W2T = (size_t)NEXP * DMODEL * FFN * 2;  //  64 MB
  const size_t SZ_XB  = (size_t)T_TOK * DMODEL * 2;       //  16 MB
  const size_t SZ_Y   = (size_t)TASSIGN * DMODEL * 2;     //  32 MB
  const size_t SZ_SMALL = (size_t)TASSIGN * 4 * 4 + 4096;
  const size_t WS_FULL = SZ_H + SZ_W1T + SZ_W2T + SZ_XB + SZ_SMALL;   // ~272.3 MB

  uint8_t* ws = (uint8_t*)d_ws;
  bool fast = (ws_size >= WS_FULL);

  size_t o = 0;
  u16* H = (u16*)(ws + o); o += SZ_H;
  u16 *w1t = nullptr, *w2t = nullptr, *Y;
  if (fast) {
    w1t = (u16*)(ws + o); o += SZ_W1T;
    w2t = (u16*)(ws + o); o += SZ_W2T;
    Y = w1t;                       // w1t is dead once GEMM2 starts writing Y
  } else {
    Y = (u16*)(ws + o); o += SZ_Y;
  }
  u16* xb = (u16*)(ws + o); o += SZ_XB;
  int*   topi    = (int*)(ws + o);   o += (size_t)TASSIGN * 4;
  float* topw    = (float*)(ws + o); o += (size_t)TASSIGN * 4;
  int*   perm    = (int*)(ws + o);   o += (size_t)TASSIGN * 4;
  int*   slotrow = (int*)(ws + o);   o += (size_t)TASSIGN * 4;
  int*   meta    = (int*)(ws + o);
  int* counts = meta, *offsets = meta + 8, *cursors = meta + 17;

  init_kernel<<<1, 64, 0, stream>>>(meta);
  gate_kernel<<<T_TOK / 4, 256, 0, stream>>>(x, Wg, topi, topw, counts, xb);
  scan_kernel<<<1, 64, 0, stream>>>(counts, offsets, cursors);
  build_kernel<<<T_TOK / 256, 256, 0, stream>>>(topi, offsets, cursors, perm, slotrow);

  if (fast) {
    transpose_kernel<<<dim3(1024, 16), 256, 0, stream>>>(w1, w2, w1t, w2t);
    // grid = NEXP * (N/256) * 32, 512 threads, XCD/expert-affine swizzle inside
    gemm8_kernel<DMODEL, FFN, true, true>
        <<<NEXP * (FFN / 256) * 32, 512, 0, stream>>>(xb, w1t, H, offsets, perm);
    gemm8_kernel<FFN, DMODEL, false, false>
        <<<NEXP * (DMODEL / 256) * 32, 512, 0, stream>>>(H, w2t, Y, offsets, perm);
  } else {
    gemm_f_kernel<DMODEL, FFN, true, true>
        <<<dim3(FFN / 128, 64, NEXP), 256, 0, stream>>>(xb, w1, H, offsets, perm);
    gemm_f_kernel<FFN, DMODEL, false, false>
        <<<dim3(DMODEL / 128, 64, NEXP), 256, 0, stream>>>(H, w2, Y, offsets, perm);
  }
  combine_kernel<<<(T_TOK * DMODEL / 4) / 256, 256, 0, stream>>>(Y, slotrow, topw, out);
}

// Round 3
// 1018.220 us; speedup vs baseline: 1.1631x; 1.0448x over previous
//
#include <hip/hip_runtime.h>
#include <stdint.h>

// Problem constants: B=4, S=2048, D=1024, E=8, F=4096, k=2 — FP32 I/O, bf16 MFMA compute
#define T_TOK   8192
#define DMODEL  1024
#define NEXP    8
#define FFN     4096
#define TASSIGN 16384   // T_TOK * k

typedef unsigned short u16;
typedef __attribute__((ext_vector_type(8))) short short8;   // MFMA bf16 A/B frag
typedef __attribute__((ext_vector_type(8))) u16 u16x8;
typedef __attribute__((ext_vector_type(4))) u16 u16x4;
typedef __attribute__((ext_vector_type(4))) float f32x4;    // MFMA C/D frag

__device__ __forceinline__ float bf2f(u16 u) {
  union { unsigned int i; float f; } v; v.i = ((unsigned int)u) << 16; return v.f;
}
__device__ __forceinline__ u16 f2bf(float f) {
  union { float f; unsigned int i; } v; v.f = f;
  unsigned int x = v.i;
  x += 0x7fffu + ((x >> 16) & 1u);   // round-to-nearest-even
  return (u16)(x >> 16);
}
// jax.nn.gelu default: approximate=True (tanh form)
__device__ __forceinline__ float gelu_tanh(float x) {
  float z = 0.7978845608028654f * x * (1.0f + 0.044715f * x * x);
  float t = 1.0f - 2.0f / (__expf(2.0f * z) + 1.0f);
  return 0.5f * x * (1.0f + t);
}
// async global->LDS, 16B per lane; LDS dest is wave-uniform base + lane*16
__device__ __forceinline__ void async16(const void* g, void* l) {
  __builtin_amdgcn_global_load_lds((__attribute__((address_space(1))) void*)g,
                                   (__attribute__((address_space(3))) void*)l,
                                   16, 0, 0);
}

// ---------------------------------------------------------------- meta init --
__global__ void init_kernel(int* __restrict__ meta) {
  if (threadIdx.x < 32) meta[threadIdx.x] = 0;
}

// ---------------------------------------------------------------- gating ----
__global__ void gate_kernel(const float* __restrict__ x, const float* __restrict__ Wg,
                            int* __restrict__ topi, float* __restrict__ topw,
                            int* __restrict__ counts, u16* __restrict__ xb) {
  __shared__ float sWg[DMODEL * NEXP];   // 32 KB
  int tid = threadIdx.x;
  for (int i = tid; i < DMODEL * NEXP / 4; i += 256)
    ((float4*)sWg)[i] = ((const float4*)Wg)[i];
  __syncthreads();

  int wave = tid >> 6, lane = tid & 63;
  int t = blockIdx.x * 4 + wave;       // grid=2048 -> t < 8192 always

  float acc[NEXP] = {0, 0, 0, 0, 0, 0, 0, 0};
  const float* xr = x + (size_t)t * DMODEL;
  u16* xbr = xb + (size_t)t * DMODEL;
  for (int d0 = 0; d0 < DMODEL; d0 += 128) {
    int d = d0 + lane * 2;
    float2 xx = *(const float2*)(xr + d);
    *(uint32_t*)(xbr + d) = (uint32_t)f2bf(xx.x) | ((uint32_t)f2bf(xx.y) << 16);
    const float* g0 = sWg + (size_t)d * NEXP;
#pragma unroll
    for (int e = 0; e < NEXP; e++)
      acc[e] += xx.x * g0[e] + xx.y * g0[NEXP + e];
  }
#pragma unroll
  for (int off = 32; off > 0; off >>= 1)
#pragma unroll
    for (int e = 0; e < NEXP; e++)
      acc[e] += __shfl_xor(acc[e], off, 64);

  if (lane == 0) {
    float v0 = -1e30f, v1 = -1e30f; int i0 = 0, i1 = 0;
#pragma unroll
    for (int e = 0; e < NEXP; e++) {           // strict > keeps earliest index on ties
      float v = acc[e];
      if (v > v0) { v1 = v0; i1 = i0; v0 = v; i0 = e; }
      else if (v > v1) { v1 = v; i1 = e; }
    }
    float e1 = __expf(v1 - v0);                // v1 <= v0
    float s = 1.0f / (1.0f + e1);
    topi[t * 2] = i0; topi[t * 2 + 1] = i1;
    topw[t * 2] = s;  topw[t * 2 + 1] = e1 * s;
    atomicAdd(&counts[i0], 1);
    atomicAdd(&counts[i1], 1);
  }
}

__global__ void scan_kernel(const int* __restrict__ counts, int* __restrict__ offsets,
                            int* __restrict__ cursors) {
  if (threadIdx.x == 0) {
    int s = 0;
    for (int e = 0; e < NEXP; e++) { offsets[e] = s; s += counts[e]; }
    offsets[NEXP] = s;
  }
  if (threadIdx.x < NEXP) cursors[threadIdx.x] = 0;
}

__global__ void build_kernel(const int* __restrict__ topi, const int* __restrict__ offsets,
                             int* __restrict__ cursors, int* __restrict__ perm,
                             int* __restrict__ slotrow) {
  int t = blockIdx.x * blockDim.x + threadIdx.x;
  if (t >= T_TOK) return;
#pragma unroll
  for (int s = 0; s < 2; s++) {
    int e = topi[t * 2 + s];
    int p = atomicAdd(&cursors[e], 1);
    int g = offsets[e] + p;
    perm[g] = t;
    slotrow[t * 2 + s] = g;
  }
}

// ------------------------------------------------------------- transpose ----
__global__ void transpose_kernel(const float* __restrict__ w1, const float* __restrict__ w2,
                                 u16* __restrict__ w1t, u16* __restrict__ w2t) {
  __shared__ u16 sh[64][72];   // +8 pad: keeps 16B store alignment, breaks bank stride
  int z = blockIdx.y;
  const float* src; u16* dst; int R, C;
  if (z < 8) { src = w1 + (size_t)z * (DMODEL * FFN); dst = w1t + (size_t)z * (FFN * DMODEL); R = DMODEL; C = FFN; }
  else       { src = w2 + (size_t)(z - 8) * (FFN * DMODEL); dst = w2t + (size_t)(z - 8) * (DMODEL * FFN); R = FFN; C = DMODEL; }
  int tilesC = C >> 6;
  int rt = blockIdx.x / tilesC, ct = blockIdx.x % tilesC;
  int tid = threadIdx.x;
#pragma unroll
  for (int i = 0; i < 2; i++) {
    int idx = i * 256 + tid;
    int r = idx >> 3, c8 = (idx & 7) * 8;
    const float* s = src + (size_t)(rt * 64 + r) * C + ct * 64 + c8;
    float4 v0 = *(const float4*)s, v1 = *(const float4*)(s + 4);
    u16* d = &sh[r][c8];
    d[0] = f2bf(v0.x); d[1] = f2bf(v0.y); d[2] = f2bf(v0.z); d[3] = f2bf(v0.w);
    d[4] = f2bf(v1.x); d[5] = f2bf(v1.y); d[6] = f2bf(v1.z); d[7] = f2bf(v1.w);
  }
  __syncthreads();
#pragma unroll
  for (int i = 0; i < 2; i++) {
    int idx = i * 256 + tid;
    int c = idx >> 3, r8 = (idx & 7) * 8;
    u16x8 v;
#pragma unroll
    for (int j = 0; j < 8; j++) v[j] = sh[r8 + j][c];
    *(u16x8*)(dst + (size_t)(ct * 64 + c) * R + rt * 64 + r8) = v;
  }
}

// --------------------------------------------- GEMM: 256x256 8-phase ---------
// C[i,n] = sum_k Arow(i)[k] * Bt[e][n][k]; A,Bt bf16 K-major.
// BM=BN=256, BK=64, 8 waves (2Mx4N), 128 KiB LDS double buffer, counted
// vmcnt(4), setprio, expert<->XCD affinity, conflict-free chunk^row swizzle.
// This round: snake quadrant order (0,0)->(0,1)->(1,1)->(1,0) with register
// fragment reuse — A-quad held across its 2 phases, B1 held ph2->ph3, B0
// re-read at ph4. ds_read_b128 per wave per K-tile: 28 (was 48). Stage
// schedule re-derived for new region deaths (A0+B1+A1 of tile t+2 staged at
// ph2/3/4 after cur-tile death; B0(t+1) staged at ph1 into the other buf).
template <int K, int N, bool GATHER, bool GELU>
__global__ __launch_bounds__(512, 2) void gemm8_kernel(
    const u16* __restrict__ A, const u16* __restrict__ Bt, u16* __restrict__ C,
    const int* __restrict__ offsets, const int* __restrict__ perm) {
  __shared__ u16 S[65536];                 // A:2x16384, B:2x16384 u16 = 128 KiB
  constexpr int NTT = N / 256;             // n tiles
  constexpr int MT  = 32;                  // m tiles (covers worst case 8192 rows)
  constexpr int NKT = K / 64;              // K-tiles (16 or 64, always even, >=2)
  (void)NTT;

  // grid = NEXP*NTT*MT; p%8 -> XCD -> expert; slot mtile-fastest (B-panel L2 reuse)
  int p = blockIdx.x;
  int e = p & 7;
  int slot = p >> 3;                       // [0, NTT*MT)
  int ntile = slot / MT;
  int mtile = slot % MT;

  int off = offsets[e];
  int nrows = offsets[e + 1] - off;
  if (mtile * 256 >= nrows) return;        // block-uniform: safe before barriers

  int tid = threadIdx.x;
  int w = tid >> 6, l = tid & 63;
  int lm = l & 15, kq = l >> 4;
  int warp_m = w >> 2, warp_n = w & 3;
  int swz = (lm & 7) << 3;                 // u16-index XOR for swizzled ds_read

  // ---- staging source pointers (per-lane, source pre-swizzled so the linear
  // global_load_lds write lands the swizzled layout)
  int scol8 = ((l & 7) ^ ((l >> 3) & 7)) * 8;
  int rbase = w * 8 + (l >> 3);            // region row, + i*64 per issue
  const u16* aptr[2][2];                   // [q half][issue]
  const u16* bptr[2][2];
  const u16* bbase = Bt + (size_t)e * ((size_t)N * K);
#pragma unroll
  for (int q = 0; q < 2; q++)
#pragma unroll
    for (int i = 0; i < 2; i++) {
      int rr = rbase + i * 64;                         // [0,128)
      int rowA = (rr < 64 ? rr : rr + 64) + q * 64;    // A-q half rows
      int gm = mtile * 256 + rowA;
      int gmc = min(gm, nrows - 1);                    // clamp: duplicates last row
      int arow = GATHER ? perm[off + gmc] : (off + gmc);
      aptr[q][i] = A + (size_t)arow * K + scol8;
      int rowB = ((rr >> 5) << 6) + (rr & 31) + q * 32; // B-q stripe rows
      bptr[q][i] = bbase + (size_t)(ntile * 256 + rowB) * K + scol8;
    }
  // wave-uniform LDS dest row bases (linear write; swizzle is on source+read)
  int arb = w * 8;                          // A: + i*128 + q*64
  int brb = (w & 3) * 8 + (w >> 2) * 64;    // B: + i*128 + q*32
  u16* As_lds = S;
  u16* Bs_lds = S + 32768;

#define STAGE_A(q, buf, kt) do {                                                       \
    async16(aptr[q][0] + (kt) * 64, As_lds + (buf) * 16384 + (arb + (q) * 64) * 64);   \
    async16(aptr[q][1] + (kt) * 64, As_lds + (buf) * 16384 + (arb + 128 + (q) * 64) * 64); \
  } while (0)
#define STAGE_B(q, buf, kt) do {                                                       \
    async16(bptr[q][0] + (kt) * 64, Bs_lds + (buf) * 16384 + (brb + (q) * 32) * 64);   \
    async16(bptr[q][1] + (kt) * 64, Bs_lds + (buf) * 16384 + (brb + 128 + (q) * 32) * 64); \
  } while (0)

  f32x4 acc[8][4];
  f32x4 zero = {0.f, 0.f, 0.f, 0.f};
#pragma unroll
  for (int i = 0; i < 8; i++)
#pragma unroll
    for (int j = 0; j < 4; j++) acc[i][j] = zero;

  short8 af[4][2], b0[2][2], b1[2][2];

#define RD_A(BUF, QM)                                                                  \
  _Pragma("unroll") for (int fi = 0; fi < 4; fi++) {                                   \
    int ml = warp_m * 128 + ((QM) * 4 + fi) * 16 + lm;                                 \
    _Pragma("unroll") for (int ks = 0; ks < 2; ks++)                                   \
      af[fi][ks] = *(const short8*)(As_lds + (BUF) * 16384 + ml * 64 +                 \
                                    ((ks * 32 + kq * 8) ^ swz));                       \
  }
#define RD_B(BUF, QN, BV)                                                              \
  _Pragma("unroll") for (int fj = 0; fj < 2; fj++) {                                   \
    int nl = warp_n * 64 + ((QN) * 2 + fj) * 16 + lm;                                  \
    _Pragma("unroll") for (int ks = 0; ks < 2; ks++)                                   \
      BV[fj][ks] = *(const short8*)(Bs_lds + (BUF) * 16384 + nl * 64 +                 \
                                    ((ks * 32 + kq * 8) ^ swz));                       \
  }
// barrier -> wait this phase's ds_reads -> fence -> prio-wrapped 16 MFMA
#define MM(QM, QN, BV)                                                                 \
  __builtin_amdgcn_s_barrier();                                                        \
  asm volatile("s_waitcnt lgkmcnt(0)" ::: "memory");                                   \
  __builtin_amdgcn_sched_barrier(0);                                                   \
  __builtin_amdgcn_s_setprio(1);                                                       \
  _Pragma("unroll") for (int fi = 0; fi < 4; fi++)                                     \
    _Pragma("unroll") for (int fj = 0; fj < 2; fj++)                                   \
      _Pragma("unroll") for (int ks = 0; ks < 2; ks++)                                 \
        acc[(QM) * 4 + fi][(QN) * 2 + fj] = __builtin_amdgcn_mfma_f32_16x16x32_bf16(   \
            af[fi][ks], BV[fj][ks], acc[(QM) * 4 + fi][(QN) * 2 + fj], 0, 0, 0);       \
  __builtin_amdgcn_s_setprio(0);

// One K-tile = 4 snake phases. KT1 = this tile index +1, KT2 = +2 (clamped).
// ph1 (0,0): read A0,B0; stage B-q0(KT1)->OBUF   [OBUF's B-q0 died prev ph4]
// ph2 (0,1): read B1;    stage A-q0(KT2)->BUF    [died ph1]
// ph3 (1,1): read A1;    stage B-q1(KT2)->BUF    [died ph2]
// ph4 (1,0): re-read B0; stage A-q1(KT2)->BUF    [died ph3]; vmcnt(4)
#define TILE(BUF, OBUF, KT1, KT2)                                                      \
  RD_A(BUF, 0) RD_B(BUF, 0, b0) STAGE_B(0, OBUF, KT1);                                 \
  MM(0, 0, b0) __builtin_amdgcn_s_barrier();                                           \
  RD_B(BUF, 1, b1) STAGE_A(0, BUF, KT2);                                               \
  MM(0, 1, b1) __builtin_amdgcn_s_barrier();                                           \
  RD_A(BUF, 1) STAGE_B(1, BUF, KT2);                                                   \
  MM(1, 1, b1) __builtin_amdgcn_s_barrier();                                           \
  RD_B(BUF, 0, b0) STAGE_A(1, BUF, KT2);                                               \
  MM(1, 0, b0)                                                                         \
  asm volatile("s_waitcnt vmcnt(4)" ::: "memory");                                     \
  __builtin_amdgcn_s_barrier();

  // ---- prologue: tile0 all 4 regions, then tile1's {A-q0, B-q1, A-q1}
  // (tile1's B-q0 is staged in-loop at tile0.ph1). vmcnt(6) = tile0 landed,
  // 3 newest stages (tile1 partials) still in flight — steady-state aging.
  STAGE_A(0, 0, 0); STAGE_B(0, 0, 0); STAGE_B(1, 0, 0); STAGE_A(1, 0, 0);
  STAGE_A(0, 1, 1); STAGE_B(1, 1, 1); STAGE_A(1, 1, 1);
  asm volatile("s_waitcnt vmcnt(6)" ::: "memory");
  __builtin_amdgcn_s_barrier();

  for (int it = 0; it < NKT / 2; it++) {
    int kt1 = 2 * it + 1;
    int t2 = min(2 * it + 2, NKT - 1);     // clamped lookahead (keeps vmcnt exact)
    int t3 = min(2 * it + 3, NKT - 1);
    TILE(0, 1, kt1, t2)
    TILE(1, 0, t2, t3)
  }

  asm volatile("s_waitcnt vmcnt(0)" ::: "memory");   // drain LDS-DMA before exit

  // C/D frag: col = lane&15, row = (lane>>4)*4 + reg
#pragma unroll
  for (int fi = 0; fi < 8; fi++) {
    int rowb = mtile * 256 + warp_m * 128 + fi * 16 + kq * 4;
#pragma unroll
    for (int r = 0; r < 4; r++) {
      int row = rowb + r;
      if (row < nrows) {
        u16* crow = C + (size_t)(off + row) * N + ntile * 256 + warp_n * 64 + lm;
#pragma unroll
        for (int fj = 0; fj < 4; fj++) {
          float v = acc[fi][fj][r];
          if (GELU) v = gelu_tanh(v);
          crow[fj * 16] = f2bf(v);
        }
      }
    }
  }
#undef STAGE_A
#undef STAGE_B
#undef RD_A
#undef RD_B
#undef MM
#undef TILE
}

// --------------------------------------------- GEMM (fallback, fp32 B) -----
template <int K, int N, bool GATHER, bool GELU>
__global__ __launch_bounds__(256) void gemm_f_kernel(
    const u16* __restrict__ A, const float* __restrict__ B, u16* __restrict__ C,
    const int* __restrict__ offsets, const int* __restrict__ perm) {
  __shared__ u16 As[128 * 32];
  __shared__ u16 Bs[128 * 32];
  int e = blockIdx.z;
  int off = offsets[e];
  int nrows = offsets[e + 1] - off;
  int mtile = blockIdx.y;
  if (mtile * 128 >= nrows) return;
  int ntile = blockIdx.x;

  int tid = threadIdx.x;
  int wave = tid >> 6, lane = tid & 63;

  int rr = tid >> 2;
  int kc = (tid & 3) * 8;
  int m0 = mtile * 128 + rr;
  int mm0 = min(m0, nrows - 1);
  int mm1 = min(m0 + 64, nrows - 1);
  const u16 *arow0, *arow1;
  if (GATHER) {
    arow0 = A + (size_t)perm[off + mm0] * K + kc;
    arow1 = A + (size_t)perm[off + mm1] * K + kc;
  } else {
    arow0 = A + (size_t)(off + mm0) * K + kc;
    arow1 = A + (size_t)(off + mm1) * K + kc;
  }

  int kk2 = (tid >> 4) * 2;
  int n8  = (tid & 15) * 8;
  const float* brow0 = B + (size_t)e * ((size_t)K * N) + (size_t)kk2 * N
                         + (size_t)ntile * 128 + n8;
  const float* brow1 = brow0 + N;

  int wm = (wave >> 1) * 64, wn = (wave & 1) * 64;
  int lm = lane & 15, kq = lane >> 4;

  f32x4 acc[4][4];
  f32x4 zero = {0.f, 0.f, 0.f, 0.f};
#pragma unroll
  for (int i = 0; i < 4; i++)
#pragma unroll
    for (int j = 0; j < 4; j++) acc[i][j] = zero;

  uint32_t* bs32 = (uint32_t*)Bs;
  for (int k0 = 0; k0 < K; k0 += 32) {
    u16x8 av0 = *(const u16x8*)(arow0 + k0);
    u16x8 av1 = *(const u16x8*)(arow1 + k0);
    float4 b00 = *(const float4*)(brow0 + (size_t)k0 * N);
    float4 b01 = *(const float4*)(brow0 + (size_t)k0 * N + 4);
    float4 b10 = *(const float4*)(brow1 + (size_t)k0 * N);
    float4 b11 = *(const float4*)(brow1 + (size_t)k0 * N + 4);
    __syncthreads();
    *(u16x8*)(As + (size_t)rr * 32 + kc) = av0;
    *(u16x8*)(As + (size_t)(rr + 64) * 32 + kc) = av1;
    int wcol = kk2 >> 1;
    bs32[(size_t)(n8 + 0) * 16 + wcol] = (uint32_t)f2bf(b00.x) | ((uint32_t)f2bf(b10.x) << 16);
    bs32[(size_t)(n8 + 1) * 16 + wcol] = (uint32_t)f2bf(b00.y) | ((uint32_t)f2bf(b10.y) << 16);
    bs32[(size_t)(n8 + 2) * 16 + wcol] = (uint32_t)f2bf(b00.z) | ((uint32_t)f2bf(b10.z) << 16);
    bs32[(size_t)(n8 + 3) * 16 + wcol] = (uint32_t)f2bf(b00.w) | ((uint32_t)f2bf(b10.w) << 16);
    bs32[(size_t)(n8 + 4) * 16 + wcol] = (uint32_t)f2bf(b01.x) | ((uint32_t)f2bf(b11.x) << 16);
    bs32[(size_t)(n8 + 5) * 16 + wcol] = (uint32_t)f2bf(b01.y) | ((uint32_t)f2bf(b11.y) << 16);
    bs32[(size_t)(n8 + 6) * 16 + wcol] = (uint32_t)f2bf(b01.z) | ((uint32_t)f2bf(b11.z) << 16);
    bs32[(size_t)(n8 + 7) * 16 + wcol] = (uint32_t)f2bf(b01.w) | ((uint32_t)f2bf(b11.w) << 16);
    __syncthreads();
    short8 a[4], b[4];
#pragma unroll
    for (int i = 0; i < 4; i++) {
      a[i] = *(const short8*)(As + (size_t)(wm + i * 16 + lm) * 32 + kq * 8);
      b[i] = *(const short8*)(Bs + (size_t)(wn + i * 16 + lm) * 32 + kq * 8);
    }
#pragma unroll
    for (int i = 0; i < 4; i++)
#pragma unroll
      for (int j = 0; j < 4; j++)
        acc[i][j] = __builtin_amdgcn_mfma_f32_16x16x32_bf16(a[i], b[j], acc[i][j], 0, 0, 0);
  }

#pragma unroll
  for (int i = 0; i < 4; i++) {
    int rbase = mtile * 128 + wm + i * 16 + kq * 4;
#pragma unroll
    for (int r = 0; r < 4; r++) {
      int row = rbase + r;
      if (row < nrows) {
        u16* crow = C + (size_t)(off + row) * N + ntile * 128 + wn + lm;
#pragma unroll
        for (int j = 0; j < 4; j++) {
          float v = acc[i][j][r];
          if (GELU) v = gelu_tanh(v);
          crow[j * 16] = f2bf(v);
        }
      }
    }
  }
}

// --------------------------------------------------------------- combine ----
__global__ void combine_kernel(const u16* __restrict__ Y, const int* __restrict__ slotrow,
                               const float* __restrict__ topw, float* __restrict__ out) {
  int idx = blockIdx.x * 256 + threadIdx.x;   // 8192 tokens * 256 chunks of 4
  int t = idx >> 8;
  int c = (idx & 255) * 4;
  int g0 = slotrow[t * 2], g1 = slotrow[t * 2 + 1];
  float w0 = topw[t * 2], w1 = topw[t * 2 + 1];
  u16x4 y0 = *(const u16x4*)(Y + (size_t)g0 * DMODEL + c);
  u16x4 y1 = *(const u16x4*)(Y + (size_t)g1 * DMODEL + c);
  float4 o;
  o.x = w0 * bf2f(y0[0]) + w1 * bf2f(y1[0]);
  o.y = w0 * bf2f(y0[1]) + w1 * bf2f(y1[1]);
  o.z = w0 * bf2f(y0[2]) + w1 * bf2f(y1[2]);
  o.w = w0 * bf2f(y0[3]) + w1 * bf2f(y1[3]);
  *(float4*)(out + (size_t)t * DMODEL + c) = o;
}

// ---------------------------------------------------------------- launch ----
extern "C" void kernel_launch(void* const* d_in, const int* in_sizes, int n_in,
                              void* d_out, int out_size, void* d_ws, size_t ws_size,
                              hipStream_t stream) {
  const float* x  = (const float*)d_in[0];
  const float* Wg = (const float*)d_in[1];
  const float* w1 = (const float*)d_in[2];
  const float* w2 = (const float*)d_in[3];
  float* out = (float*)d_out;

  const size_t SZ_H   = (size_t)TASSIGN * FFN * 2;        // 128 MB
  const size_t SZ_W1T = (size_t)NEXP * FFN * DMODEL * 2;  //  64 MB (Y aliases: needs 32 MB)
  const size_t SZ_W2T = (size_t)NEXP * DMODEL * FFN * 2;  //  64 MB
  const size_t SZ_XB  = (size_t)T_TOK * DMODEL * 2;       //  16 MB
  const size_t SZ_Y   = (size_t)TASSIGN * DMODEL * 2;     //  32 MB
  const size_t SZ_SMALL = (size_t)TASSIGN * 4 * 4 + 4096;
  const size_t WS_FULL = SZ_H + SZ_W1T + SZ_W2T + SZ_XB + SZ_SMALL;   // ~272.3 MB

  uint8_t* ws = (uint8_t*)d_ws;
  bool fast = (ws_size >= WS_FULL);

  size_t o = 0;
  u16* H = (u16*)(ws + o); o += SZ_H;
  u16 *w1t = nullptr, *w2t = nullptr, *Y;
  if (fast) {
    w1t = (u16*)(ws + o); o += SZ_W1T;
    w2t = (u16*)(ws + o); o += SZ_W2T;
    Y = w1t;                       // w1t is dead once GEMM2 starts writing Y
  } else {
    Y = (u16*)(ws + o); o += SZ_Y;
  }
  u16* xb = (u16*)(ws + o); o += SZ_XB;
  int*   topi    = (int*)(ws + o);   o += (size_t)TASSIGN * 4;
  float* topw    = (float*)(ws + o); o += (size_t)TASSIGN * 4;
  int*   perm    = (int*)(ws + o);   o += (size_t)TASSIGN * 4;
  int*   slotrow = (int*)(ws + o);   o += (size_t)TASSIGN * 4;
  int*   meta    = (int*)(ws + o);
  int* counts = meta, *offsets = meta + 8, *cursors = meta + 17;

  init_kernel<<<1, 64, 0, stream>>>(meta);
  gate_kernel<<<T_TOK / 4, 256, 0, stream>>>(x, Wg, topi, topw, counts, xb);
  scan_kernel<<<1, 64, 0, stream>>>(counts, offsets, cursors);
  build_kernel<<<T_TOK / 256, 256, 0, stream>>>(topi, offsets, cursors, perm, slotrow);

  if (fast) {
    transpose_kernel<<<dim3(1024, 16), 256, 0, stream>>>(w1, w2, w1t, w2t);
    // grid = NEXP * (N/256) * 32, 512 threads, XCD/expert-affine swizzle inside
    gemm8_kernel<DMODEL, FFN, true, true>
        <<<NEXP * (FFN / 256) * 32, 512, 0, stream>>>(xb, w1t, H, offsets, perm);
    gemm8_kernel<FFN, DMODEL, false, false>
        <<<NEXP * (DMODEL / 256) * 32, 512, 0, stream>>>(H, w2t, Y, offsets, perm);
  } else {
    gemm_f_kernel<DMODEL, FFN, true, true>
        <<<dim3(FFN / 128, 64, NEXP), 256, 0, stream>>>(xb, w1, H, offsets, perm);
    gemm_f_kernel<FFN, DMODEL, false, false>
        <<<dim3(DMODEL / 128, 64, NEXP), 256, 0, stream>>>(H, w2, Y, offsets, perm);
  }
  combine_kernel<<<(T_TOK * DMODEL / 4) / 256, 256, 0, stream>>>(Y, slotrow, topw, out);
}